// Round 6
// baseline (204.901 us; speedup 1.0000x reference)
//
#include <hip/hip_runtime.h>
#include <hip/hip_bf16.h>
#include <cstdint>
#include <cstddef>

typedef __bf16 bf16;
typedef __bf16 bf16x8 __attribute__((ext_vector_type(8)));
typedef __bf16 bf16x4 __attribute__((ext_vector_type(4)));
typedef __bf16 bf16x2 __attribute__((ext_vector_type(2)));
typedef float f32x4 __attribute__((ext_vector_type(4)));
typedef float f32x16 __attribute__((ext_vector_type(16)));
typedef unsigned int u32;
typedef u32 u32x4 __attribute__((ext_vector_type(4)));

#define LDS_CAST(p) (__attribute__((address_space(3))) void*)(p)
#define GLB_CAST(p) (const __attribute__((address_space(1))) void*)(p)
#define MFMA16(a, b, c) __builtin_amdgcn_mfma_f32_16x16x32_bf16(a, b, c, 0, 0, 0)
#define MFMA32(a, b, c) __builtin_amdgcn_mfma_f32_32x32x16_bf16(a, b, c, 0, 0, 0)

#if __has_builtin(__builtin_amdgcn_exp2f)
#define EXPF(x) __builtin_amdgcn_exp2f(x)
#define QK_SCALE 0.18033688011112042f  /* 0.125 * log2(e) */
#else
#define EXPF(x) __expf(x)
#define QK_SCALE 0.125f
#endif

static constexpr int BATCH = 8;
static constexpr int NSEQ  = 1024;
static constexpr int CDIM  = 768;
static constexpr int NH    = 12;
static constexpr int HD    = 64;
static constexpr int MTOT  = BATCH * NSEQ;   // 8192
static constexpr int NC3   = 3 * CDIM;       // 2304

// Fixed softmax shift (log2 domain; scale*log2e folded into Q).
static constexpr float M_FIX = 12.0f;

__device__ inline u32 pkbf(float a, float b) {
    bf16x2 t = { (bf16)a, (bf16)b };
    return __builtin_bit_cast(u32, t);
}

// ---------------- cast fp32 -> bf16 (vectorized) ----------------
__global__ void cast_kernel(const float* __restrict__ src, bf16* __restrict__ dst, int n4) {
    int i = blockIdx.x * blockDim.x + threadIdx.x;
    if (i < n4) {
        float4 v = ((const float4*)src)[i];
        bf16x4 o = { (bf16)v.x, (bf16)v.y, (bf16)v.z, (bf16)v.w };
        ((bf16x4*)dst)[i] = o;
    }
}

// ------------- tiled transpose-cast: dst[n][k] = (bf16)src[k][n] -------------
__global__ void tcast_kernel(const float* __restrict__ src, bf16* __restrict__ dst,
                             int K, int N) {
    __shared__ float tile[32][33];
    const int n0 = blockIdx.x * 32, k0 = blockIdx.y * 32;
    const int tx = threadIdx.x & 31, ty = threadIdx.x >> 5;   // ty 0..7
#pragma unroll
    for (int p = 0; p < 4; p++)
        tile[ty + p * 8][tx] = src[(size_t)(k0 + ty + p * 8) * N + n0 + tx];
    __syncthreads();
#pragma unroll
    for (int p = 0; p < 4; p++)
        dst[(size_t)(n0 + ty + p * 8) * K + k0 + tx] = (bf16)tile[tx][ty + p * 8];
}

// ---------------- GEMM: C[M,Nd] = A[M,K] @ Bt[Nd,K]^T + bias ----------------
// Square BMxBM tile. BM=256: 512 thr, 8 waves (2Mx4N), per-wave 128x64, LDS 128KB.
// BM=128: 256 thr, 4 waves (2Mx2N), per-wave 64x64, LDS 64KB (2 blk/CU).
// T3+T4 counted-vmcnt pipeline over 24 subphases of BK=32:
//   4 LDS regions (2 dbuf x 2 k-half, (BM+BN)*32 elems each). Subphase u reads
//   region u&3 and issues the 4-load stage for subphase u+2 into region (u+2)&3.
//   End of u: s_waitcnt vmcnt(4) -> stage(u+1) landed, stage(u+2) stays in flight.
//   Never drains in the main loop (T4); each stage gets a full 32-MFMA cluster +
//   barrier of slack before its wait. Region (u+2)&3 last read at u-2, whose
//   ds_reads complete (lgkmcnt before MFMA) before its end barrier -> overwrite
//   issued >= 2 barriers later: race-free.
// LDS swizzle: slot (row, cs) holds global chunk cs ^ ((row>>1)&3); reads at
// chunk quad ^ ((l16>>1)&3) -> 2-way (free); verified: SQ_LDS_BANK_CONFLICT = 0.
// MODE 0: fp32 out (proj). MODE 1: bf16 q/k -> [B,H,N,D] (q pre-scaled), v -> [B,H,D,N]
template <int MODE, int BM>
__global__ __launch_bounds__(BM * 2, BM == 256 ? 2 : 4) void gemm_kernel(
    const bf16* __restrict__ A, const bf16* __restrict__ Bt,
    const float* __restrict__ bias, float* __restrict__ outf,
    bf16* __restrict__ q, bf16* __restrict__ kk, bf16* __restrict__ v,
    int Ndim, int K)
{
    constexpr int BN  = BM;
    constexpr int MI  = BM / 32;          // M-fragments per wave (8 or 4)
    constexpr int WNC = BN / 64;          // waves along N (4 or 2)
    constexpr int REG = (BM + BN) * 32;   // region size in elems (16384 / 8192)
    __shared__ alignas(16) bf16 sAB[4][REG];
    const int tid  = threadIdx.x;
    const int lane = tid & 63;
    const int quad = lane >> 4;
    const int l16  = lane & 15;
    const int wid  = tid >> 6;
    const int wmI  = wid / WNC;           // 0..1
    const int wnI  = wid % WNC;           // 0..WNC-1

    const int wg = blockIdx.x;
    const int x  = (wg & 7) * (gridDim.x >> 3) + (wg >> 3);
    const int nTn = Ndim / BN;
    const int tn = x % nTn, tm = x / nTn;
    const int tmB = tm * BM, tnB = tn * BN;

    int aoff[MI], boff[4];
    {
        const int xr = ((quad ^ ((l16 >> 1) & 3)) << 3);
#pragma unroll
        for (int i = 0; i < MI; i++) aoff[i] = (wmI * (BM / 2) + i * 16 + l16) * 32 + xr;
#pragma unroll
        for (int j = 0; j < 4; j++) boff[j] = BM * 32 + (wnI * 64 + j * 16 + l16) * 32 + xr;
    }

    // staging: slot s=(r0, tid&3); fetch global chunk (tid&3) ^ ((r0>>1)&3)
    const int r0 = tid >> 2;              // 0..BM/2-1
    const int c0 = (tid & 3) ^ ((r0 >> 1) & 3);
    const bf16* gA0 = A  + (size_t)(tmB + r0) * K + c0 * 8;
    const bf16* gA1 = gA0 + (size_t)(BM / 2) * K;
    const bf16* gB0 = Bt + (size_t)(tnB + r0) * K + c0 * 8;
    const bf16* gB1 = gB0 + (size_t)(BN / 2) * K;
    const int ldsb = (tid & ~63) * 8;     // wave-uniform slot base (elems)

    auto STAGE32 = [&](int u) {           // stage k-chunk u (32 wide) into region u&3
        const int k0 = u << 5;
        bf16* d = &sAB[u & 3][0] + ldsb;
        __builtin_amdgcn_global_load_lds(GLB_CAST(gA0 + k0), LDS_CAST(d),                              16, 0, 0);
        __builtin_amdgcn_global_load_lds(GLB_CAST(gA1 + k0), LDS_CAST(d + (BM / 2) * 32),              16, 0, 0);
        __builtin_amdgcn_global_load_lds(GLB_CAST(gB0 + k0), LDS_CAST(d + BM * 32),                    16, 0, 0);
        __builtin_amdgcn_global_load_lds(GLB_CAST(gB1 + k0), LDS_CAST(d + BM * 32 + (BN / 2) * 32),    16, 0, 0);
    };

    const f32x4 fzero = {0.f, 0.f, 0.f, 0.f};
    f32x4 acc[MI][4];
#pragma unroll
    for (int i = 0; i < MI; i++)
#pragma unroll
        for (int j = 0; j < 4; j++) acc[i][j] = fzero;

    const int NT2 = K >> 5;   // 24 subphases for K=768
    STAGE32(0);
    STAGE32(1);
    asm volatile("s_waitcnt vmcnt(4)" ::: "memory");   // chunk 0 landed; chunk 1 in flight
    __builtin_amdgcn_sched_barrier(0);
    __builtin_amdgcn_s_barrier();

    for (int u = 0; u < NT2; ++u) {
        if (u + 2 < NT2) STAGE32(u + 2);

        const bf16* buf = &sAB[u & 3][0];
        bf16x8 af[MI], bfr[4];
#pragma unroll
        for (int i = 0; i < MI; i++) af[i]  = *(const bf16x8*)(buf + aoff[i]);
#pragma unroll
        for (int j = 0; j < 4; j++)  bfr[j] = *(const bf16x8*)(buf + boff[j]);

        __builtin_amdgcn_s_setprio(1);
#pragma unroll
        for (int i = 0; i < MI; i++)
#pragma unroll
            for (int j = 0; j < 4; j++) acc[i][j] = MFMA16(af[i], bfr[j], acc[i][j]);
        __builtin_amdgcn_s_setprio(0);

        if (u < NT2 - 1) {
            if (u + 2 < NT2) asm volatile("s_waitcnt vmcnt(4)" ::: "memory");
            else             asm volatile("s_waitcnt vmcnt(0)" ::: "memory");
            __builtin_amdgcn_sched_barrier(0);
            __builtin_amdgcn_s_barrier();
            __builtin_amdgcn_sched_barrier(0);
        }
    }

    if (MODE == 0) {
#pragma unroll
        for (int i = 0; i < MI; i++) {
            int row = tmB + wmI * (BM / 2) + i * 16 + quad * 4;
#pragma unroll
            for (int j = 0; j < 4; j++) {
                int col = tnB + wnI * 64 + j * 16 + l16;
                float bv = bias[col];
                float* op = outf + (size_t)row * Ndim + col;
#pragma unroll
                for (int r = 0; r < 4; r++) op[(size_t)r * Ndim] = acc[i][j][r] + bv;
            }
        }
    } else {
#pragma unroll
        for (int i = 0; i < MI; i++) {
            int row = tmB + wmI * (BM / 2) + i * 16 + quad * 4;
            int b  = row >> 10;
            int ns = row & 1023;
#pragma unroll
            for (int j = 0; j < 4; j++) {
                int col = tnB + wnI * 64 + j * 16 + l16;
                int t3  = col / 768;
                int rem = col - t3 * 768;
                int h = rem >> 6;
                int d = rem & 63;
                float bv = bias[col];
                if (t3 == 0) {
                    bf16* qp = q + ((size_t)(b * NH + h) * NSEQ + ns) * HD + d;
#pragma unroll
                    for (int r = 0; r < 4; r++)
                        qp[(size_t)r * HD] = (bf16)((acc[i][j][r] + bv) * (float)QK_SCALE);
                } else if (t3 == 1) {
                    bf16* kp = kk + ((size_t)(b * NH + h) * NSEQ + ns) * HD + d;
#pragma unroll
                    for (int r = 0; r < 4; r++) kp[(size_t)r * HD] = (bf16)(acc[i][j][r] + bv);
                } else {
                    bf16x4 pv = { (bf16)(acc[i][j][0] + bv), (bf16)(acc[i][j][1] + bv),
                                  (bf16)(acc[i][j][2] + bv), (bf16)(acc[i][j][3] + bv) };
                    *(bf16x4*)(v + ((size_t)(b * NH + h) * HD + d) * NSEQ + ns) = pv;
                }
            }
        }
    }
}

// ---------------- flash attention, fixed-m softmax, 32x32 MFMA ----------------
// q (pre-scaled by 0.125*log2e): [B,H,N,D]; k: [B,H,N,D]; v: [B,H,D,N]; o: [B,N,C]
// P = exp2(S_log2 - M_FIX); denominator on the MFMA pipe via ones-row A-operand.
// MFMA chains interleaved (kvt/dt inner). Grid: 1D 768 blocks, XCD-locality map.
__global__ __launch_bounds__(256) void attn_kernel(
    const bf16* __restrict__ q, const bf16* __restrict__ k,
    const bf16* __restrict__ v, bf16* __restrict__ o)
{
    __shared__ alignas(16) bf16 sKV[2][8192];
    const int tid  = threadIdx.x;
    const int lane = tid & 63;
    const int w    = tid >> 6;
    const int h    = lane >> 5;
    const int l32  = lane & 31;

    const int wg  = blockIdx.x;          // 0..767
    const int xcd = wg & 7;
    const int idx = wg >> 3;             // 0..95
    const int bh  = xcd * 12 + (idx % 12);
    const int qt  = idx / 12;            // 0..7
    const int b = bh / NH, hh = bh - b * NH;

    const bf16* qb = q + ((size_t)bh * NSEQ + qt * 128) * HD;
    const bf16* kb = k + (size_t)bh * NSEQ * HD;
    const bf16* vb = v + (size_t)bh * HD * NSEQ;

#pragma unroll
    for (int i = 0; i < 4; i++) {
        int slot = w * 256 + i * 64 + lane;
        int r = slot >> 3, cs = slot & 7;
        __builtin_amdgcn_global_load_lds(GLB_CAST(qb + r * HD + ((cs ^ (r & 7)) * 8)),
                                         LDS_CAST(&sKV[1][(w * 256 + i * 64) * 8]), 16, 0, 0);
    }
    auto stageKV = [&](int kt, int buf) {
#pragma unroll
        for (int i = 0; i < 2; i++) {
            int slot = w * 128 + i * 64 + lane;
            int r = slot >> 3, cs = slot & 7;
            int cc = (cs ^ (r & 7)) * 8;
            __builtin_amdgcn_global_load_lds(GLB_CAST(kb + (size_t)(kt * 64 + r) * HD + cc),
                                             LDS_CAST(&sKV[buf][(w * 128 + i * 64) * 8]), 16, 0, 0);
            __builtin_amdgcn_global_load_lds(GLB_CAST(vb + (size_t)r * NSEQ + kt * 64 + cc),
                                             LDS_CAST(&sKV[buf][4096 + (w * 128 + i * 64) * 8]), 16, 0, 0);
        }
    };
    stageKV(0, 0);
    __syncthreads();   // drains Q + buf0

    bf16x8 qf[4];
    {
        int row = w * 32 + l32, rxq = row & 7;
#pragma unroll
        for (int cd = 0; cd < 4; cd++)
            qf[cd] = *(const bf16x8*)(&sKV[1][(row * 8 + ((2 * cd + h) ^ rxq)) * 8]);
    }

    bf16x8 onesA;
#pragma unroll
    for (int i = 0; i < 8; i++) onesA[i] = (bf16)1.0f;

    f32x16 accO[2], accL;
#pragma unroll
    for (int dt = 0; dt < 2; dt++)
#pragma unroll
        for (int i = 0; i < 16; i++) accO[dt][i] = 0.f;
#pragma unroll
    for (int i = 0; i < 16; i++) accL[i] = 0.f;

    const int rx = l32 & 7;

    for (int kt = 0; kt < 16; kt++) {
        const int cur = kt & 1;
        __syncthreads();
        if (kt < 15) stageKV(kt + 1, 1 - cur);
        const bf16* sKc = &sKV[cur][0];
        const bf16* sVc = &sKV[cur][4096];

        f32x16 accS[2];
#pragma unroll
        for (int kvt = 0; kvt < 2; kvt++)
#pragma unroll
            for (int i = 0; i < 16; i++) accS[kvt][i] = 0.f;
        __builtin_amdgcn_s_setprio(1);
#pragma unroll
        for (int cd = 0; cd < 4; cd++)
#pragma unroll
            for (int kvt = 0; kvt < 2; kvt++) {
                int row = kvt * 32 + l32;
                bf16x8 kf = *(const bf16x8*)(sKc + (row * 8 + ((2 * cd + h) ^ rx)) * 8);
                accS[kvt] = MFMA32(kf, qf[cd], accS[kvt]);
            }
        __builtin_amdgcn_s_setprio(0);

        u32 pr[2][4][2];
#pragma unroll
        for (int kvt = 0; kvt < 2; kvt++)
#pragma unroll
            for (int g = 0; g < 4; g++) {
                pr[kvt][g][0] = pkbf(EXPF(accS[kvt][4 * g + 0] - M_FIX),
                                     EXPF(accS[kvt][4 * g + 1] - M_FIX));
                pr[kvt][g][1] = pkbf(EXPF(accS[kvt][4 * g + 2] - M_FIX),
                                     EXPF(accS[kvt][4 * g + 3] - M_FIX));
            }

        bf16x8 pf[4];
#pragma unroll
        for (int c = 0; c < 4; c++) {
            int kvt = c >> 1, c1 = c & 1;
            u32 u00 = pr[kvt][2 * c1][0],     u01 = pr[kvt][2 * c1][1];
            u32 u10 = pr[kvt][2 * c1 + 1][0], u11 = pr[kvt][2 * c1 + 1][1];
            u32 y0 = h ? u10 : u00, y1 = h ? u11 : u01;
            u32 z0 = h ? u00 : u10, z1 = h ? u01 : u11;
            u32 w0 = (u32)__shfl_xor((int)z0, 32);
            u32 w1 = (u32)__shfl_xor((int)z1, 32);
            u32x4 fv = { h ? w0 : y0, h ? w1 : y1, h ? y0 : w0, h ? y1 : w1 };
            pf[c] = __builtin_bit_cast(bf16x8, fv);
        }

        __builtin_amdgcn_s_setprio(1);
#pragma unroll
        for (int c = 0; c < 4; c++) {
#pragma unroll
            for (int dt = 0; dt < 2; dt++) {
                int row = dt * 32 + l32;
                bf16x8 vf = *(const bf16x8*)(sVc + (row * 8 + ((2 * c + h) ^ rx)) * 8);
                accO[dt] = MFMA32(vf, pf[c], accO[dt]);
            }
            accL = MFMA32(onesA, pf[c], accL);
        }
        __builtin_amdgcn_s_setprio(0);
    }

    float inv = 1.f / accL[0];
    bf16* ob = o + ((size_t)b * NSEQ + qt * 128 + w * 32 + l32) * CDIM + hh * HD;
#pragma unroll
    for (int dt = 0; dt < 2; dt++)
#pragma unroll
        for (int g = 0; g < 4; g++) {
            bf16x4 t = { (bf16)(accO[dt][4 * g + 0] * inv), (bf16)(accO[dt][4 * g + 1] * inv),
                         (bf16)(accO[dt][4 * g + 2] * inv), (bf16)(accO[dt][4 * g + 3] * inv) };
            *(bf16x4*)(ob + dt * 32 + 8 * g + 4 * h) = t;
        }
}

// ---------------------------------------------------------------
extern "C" void kernel_launch(void* const* d_in, const int* in_sizes, int n_in,
                              void* d_out, int out_size, void* d_ws, size_t ws_size,
                              hipStream_t stream)
{
    const float* x     = (const float*)d_in[0];
    const float* Wqkv  = (const float*)d_in[1];
    const float* bqkv  = (const float*)d_in[2];
    const float* Wproj = (const float*)d_in[3];
    const float* bproj = (const float*)d_in[4];
    float* out = (float*)d_out;

    char* ws = (char*)d_ws;
    const size_t MC2 = (size_t)MTOT * CDIM * 2;
    bf16* xb     = (bf16*)ws; ws += MC2;
    bf16* wqkvt  = (bf16*)ws; ws += (size_t)NC3 * CDIM * 2;
    bf16* wprojt = (bf16*)ws; ws += (size_t)CDIM * CDIM * 2;
    bf16* qw     = (bf16*)ws; ws += MC2;
    bf16* kw     = (bf16*)ws; ws += MC2;
    bf16* vw     = (bf16*)ws; ws += MC2;
    bf16* ow     = (bf16*)ws; ws += MC2;

    int n4 = MTOT * CDIM / 4;
    cast_kernel<<<dim3((n4 + 255) / 256), dim3(256), 0, stream>>>(x, xb, n4);
    tcast_kernel<<<dim3(NC3 / 32, CDIM / 32), dim3(256), 0, stream>>>(Wqkv,  wqkvt,  CDIM, NC3);
    tcast_kernel<<<dim3(CDIM / 32, CDIM / 32), dim3(256), 0, stream>>>(Wproj, wprojt, CDIM, CDIM);

    // QKV: 256x256 tiles -> 9*32 = 288 blocks (%8==0 for XCD swizzle), 512 thr
    gemm_kernel<1, 256><<<dim3((NC3 / 256) * (MTOT / 256)), dim3(512), 0, stream>>>(
        xb, wqkvt, bqkv, nullptr, qw, kw, vw, NC3, CDIM);

    attn_kernel<<<dim3(768), dim3(256), 0, stream>>>(qw, kw, vw, ow);

    // proj: 128x128 tiles -> 6*64 = 384 blocks (%8==0), 256 thr
    gemm_kernel<0, 128><<<dim3((CDIM / 128) * (MTOT / 128)), dim3(256), 0, stream>>>(
        ow, wprojt, bproj, out, nullptr, nullptr, nullptr, CDIM, CDIM);
}

// Round 7
// 193.762 us; speedup vs baseline: 1.0575x; 1.0575x over previous
//
#include <hip/hip_runtime.h>
#include <hip/hip_bf16.h>
#include <cstdint>
#include <cstddef>

typedef __bf16 bf16;
typedef __bf16 bf16x8 __attribute__((ext_vector_type(8)));
typedef __bf16 bf16x4 __attribute__((ext_vector_type(4)));
typedef __bf16 bf16x2 __attribute__((ext_vector_type(2)));
typedef float f32x4 __attribute__((ext_vector_type(4)));
typedef float f32x16 __attribute__((ext_vector_type(16)));
typedef unsigned int u32;
typedef u32 u32x4 __attribute__((ext_vector_type(4)));

#define LDS_CAST(p) (__attribute__((address_space(3))) void*)(p)
#define GLB_CAST(p) (const __attribute__((address_space(1))) void*)(p)
#define MFMA16(a, b, c) __builtin_amdgcn_mfma_f32_16x16x32_bf16(a, b, c, 0, 0, 0)
#define MFMA32(a, b, c) __builtin_amdgcn_mfma_f32_32x32x16_bf16(a, b, c, 0, 0, 0)

#if __has_builtin(__builtin_amdgcn_exp2f)
#define EXPF(x) __builtin_amdgcn_exp2f(x)
#define QK_SCALE 0.18033688011112042f  /* 0.125 * log2(e) */
#else
#define EXPF(x) __expf(x)
#define QK_SCALE 0.125f
#endif

static constexpr int BATCH = 8;
static constexpr int NSEQ  = 1024;
static constexpr int CDIM  = 768;
static constexpr int NH    = 12;
static constexpr int HD    = 64;
static constexpr int MTOT  = BATCH * NSEQ;   // 8192
static constexpr int NC3   = 3 * CDIM;       // 2304

// Fixed softmax shift (log2 domain; scale*log2e folded into Q).
static constexpr float M_FIX = 12.0f;

// prep kernel work partition
static constexpr int TQKV  = (NC3 / 32) * (CDIM / 32);   // 1728 transpose tiles
static constexpr int TPROJ = (CDIM / 32) * (CDIM / 32);  // 576
static constexpr int TT    = TQKV + TPROJ;               // 2304
static constexpr int N4    = MTOT * CDIM / 4;            // 1572864 float4 items
static constexpr int CASTB = (N4 + 255) / 256;           // 6144 cast blocks

__device__ inline u32 pkbf(float a, float b) {
    bf16x2 t = { (bf16)a, (bf16)b };
    return __builtin_bit_cast(u32, t);
}

// ---------- fused prep: x cast + Wqkv^T cast + Wproj^T cast (1 launch) ----------
__global__ void prep_kernel(const float* __restrict__ x, bf16* __restrict__ xb,
                            const float* __restrict__ Wqkv, bf16* __restrict__ wqkvt,
                            const float* __restrict__ Wproj, bf16* __restrict__ wprojt)
{
    __shared__ float tile[32][33];
    const int bid = blockIdx.x;
    if (bid < TT) {
        // tiled transpose-cast: dst[n][k] = (bf16)src[k][n]; coalesced both sides
        const float* src; bf16* dst; int N, n0, k0;
        if (bid < TQKV) { src = Wqkv;  dst = wqkvt;  N = NC3;
                          n0 = (bid % (NC3 / 32)) * 32;  k0 = (bid / (NC3 / 32)) * 32; }
        else { int t = bid - TQKV; src = Wproj; dst = wprojt; N = CDIM;
               n0 = (t % (CDIM / 32)) * 32;  k0 = (t / (CDIM / 32)) * 32; }
        const int K = CDIM;
        const int tx = threadIdx.x & 31, ty = threadIdx.x >> 5;   // ty 0..7
#pragma unroll
        for (int p = 0; p < 4; p++)
            tile[ty + p * 8][tx] = src[(size_t)(k0 + ty + p * 8) * N + n0 + tx];
        __syncthreads();
#pragma unroll
        for (int p = 0; p < 4; p++)
            dst[(size_t)(n0 + ty + p * 8) * K + k0 + tx] = (bf16)tile[tx][ty + p * 8];
    } else {
        int i = (bid - TT) * 256 + threadIdx.x;
        if (i < N4) {
            float4 v = ((const float4*)x)[i];
            bf16x4 o = { (bf16)v.x, (bf16)v.y, (bf16)v.z, (bf16)v.w };
            ((bf16x4*)xb)[i] = o;
        }
    }
}

// ---------------- GEMM: C[M,Nd] = A[M,K] @ Bt[Nd,K]^T + bias ----------------
// BM x 128 tile (BM=256: 8 waves; BM=128: 4 waves), per-wave 64x64, BK=32.
// DOUBLE-buffered LDS, prefetch depth 1 (m97 sync pattern), 48KB (BM=256).
// LDS swizzle: slot (row, cs) holds global chunk cs ^ ((row>>1)&3); reads at
// chunk quad ^ ((l16>>1)&3) -> 2-way (free). Verified: SQ_LDS_BANK_CONFLICT = 0.
// MODE 0: fp32 out (proj). MODE 1: bf16 q/k -> [B,H,N,D] (q pre-scaled), v -> [B,H,D,N]
template <int MODE, int BM>
__global__ __launch_bounds__(BM * 2, 4) void gemm_kernel(
    const bf16* __restrict__ A, const bf16* __restrict__ Bt,
    const float* __restrict__ bias, float* __restrict__ outf,
    bf16* __restrict__ q, bf16* __restrict__ kk, bf16* __restrict__ v,
    int Ndim, int K)
{
    constexpr int BN = 128;
    __shared__ alignas(16) bf16 sAB[2][(BM + BN) * 32];
    const int tid  = threadIdx.x;
    const int lane = tid & 63;
    const int quad = lane >> 4;
    const int l16  = lane & 15;
    const int wid  = tid >> 6;
    const int wmI  = wid >> 1;
    const int wnI  = wid & 1;

    const int wg = blockIdx.x;
    const int x  = (wg & 7) * (gridDim.x >> 3) + (wg >> 3);
    const int nTn = Ndim >> 7;
    const int tn = x % nTn, tm = x / nTn;
    const int tmB = tm * BM, tnB = tn * BN;

    int aoff[4], boff[4];
    {
        const int xr = ((quad ^ ((l16 >> 1) & 3)) << 3);
#pragma unroll
        for (int i = 0; i < 4; i++) aoff[i] = (wmI * 64 + i * 16 + l16) * 32 + xr;
#pragma unroll
        for (int j = 0; j < 4; j++) boff[j] = BM * 32 + (wnI * 64 + j * 16 + l16) * 32 + xr;
    }

    const int r0 = tid >> 2;
    const int c0 = (tid & 3) ^ ((r0 >> 1) & 3);
    const bf16* gA0 = A  + (size_t)(tmB + r0) * K + c0 * 8;
    const bf16* gA1 = gA0 + (size_t)(BM / 2) * K;
    const bf16* gB0 = Bt + (size_t)(tnB + r0) * K + c0 * 8;
    const bf16* gB1 = gB0 + (size_t)64 * K;           // used only when BM==128
    const int ldsb = (tid & ~63) * 8;                 // wave-uniform slot base (elems)

    auto STAGE = [&](int t, int bsel) {
        const int k0 = t << 5;
        bf16* d = &sAB[bsel][0] + ldsb;
        if constexpr (BM == 256) {
            __builtin_amdgcn_global_load_lds(GLB_CAST(gA0 + k0), LDS_CAST(d),        16, 0, 0);
            __builtin_amdgcn_global_load_lds(GLB_CAST(gA1 + k0), LDS_CAST(d + 4096), 16, 0, 0);
            __builtin_amdgcn_global_load_lds(GLB_CAST(gB0 + k0), LDS_CAST(d + 8192), 16, 0, 0);
        } else {
            __builtin_amdgcn_global_load_lds(GLB_CAST(gA0 + k0), LDS_CAST(d),        16, 0, 0);
            __builtin_amdgcn_global_load_lds(GLB_CAST(gA1 + k0), LDS_CAST(d + 2048), 16, 0, 0);
            __builtin_amdgcn_global_load_lds(GLB_CAST(gB0 + k0), LDS_CAST(d + 4096), 16, 0, 0);
            __builtin_amdgcn_global_load_lds(GLB_CAST(gB1 + k0), LDS_CAST(d + 6144), 16, 0, 0);
        }
    };

    const f32x4 fzero = {0.f, 0.f, 0.f, 0.f};
    f32x4 acc[4][4];
#pragma unroll
    for (int i = 0; i < 4; i++)
#pragma unroll
        for (int j = 0; j < 4; j++) acc[i][j] = fzero;

    const int NT = K >> 5;   // 24 for K=768
    STAGE(0, 0);

    int bsel = 0;
    for (int t = 0; t < NT; ++t) {
        asm volatile("s_waitcnt vmcnt(0)" ::: "memory");   // tile t staged by all waves
        __builtin_amdgcn_sched_barrier(0);
        __builtin_amdgcn_s_barrier();
        if (t + 1 < NT) STAGE(t + 1, bsel ^ 1);            // overwrite-safe: after barrier

        const bf16* buf = &sAB[bsel][0];
        bf16x8 af[4], bfr[4];
#pragma unroll
        for (int i = 0; i < 4; i++) af[i]  = *(const bf16x8*)(buf + aoff[i]);
#pragma unroll
        for (int j = 0; j < 4; j++) bfr[j] = *(const bf16x8*)(buf + boff[j]);

        __builtin_amdgcn_s_setprio(1);
#pragma unroll
        for (int i = 0; i < 4; i++)
#pragma unroll
            for (int j = 0; j < 4; j++) acc[i][j] = MFMA16(af[i], bfr[j], acc[i][j]);
        __builtin_amdgcn_s_setprio(0);
        bsel ^= 1;
    }

    if (MODE == 0) {
#pragma unroll
        for (int i = 0; i < 4; i++) {
            int row = tmB + wmI * 64 + i * 16 + quad * 4;
#pragma unroll
            for (int j = 0; j < 4; j++) {
                int col = tnB + wnI * 64 + j * 16 + l16;
                float bv = bias[col];
                float* op = outf + (size_t)row * Ndim + col;
#pragma unroll
                for (int r = 0; r < 4; r++) op[(size_t)r * Ndim] = acc[i][j][r] + bv;
            }
        }
    } else {
#pragma unroll
        for (int i = 0; i < 4; i++) {
            int row = tmB + wmI * 64 + i * 16 + quad * 4;
            int b  = row >> 10;
            int ns = row & 1023;
#pragma unroll
            for (int j = 0; j < 4; j++) {
                int col = tnB + wnI * 64 + j * 16 + l16;
                int t3  = col / 768;
                int rem = col - t3 * 768;
                int h = rem >> 6;
                int d = rem & 63;
                float bv = bias[col];
                if (t3 == 0) {
                    bf16* qp = q + ((size_t)(b * NH + h) * NSEQ + ns) * HD + d;
#pragma unroll
                    for (int r = 0; r < 4; r++)
                        qp[(size_t)r * HD] = (bf16)((acc[i][j][r] + bv) * (float)QK_SCALE);
                } else if (t3 == 1) {
                    bf16* kp = kk + ((size_t)(b * NH + h) * NSEQ + ns) * HD + d;
#pragma unroll
                    for (int r = 0; r < 4; r++) kp[(size_t)r * HD] = (bf16)(acc[i][j][r] + bv);
                } else {
                    bf16x4 pv = { (bf16)(acc[i][j][0] + bv), (bf16)(acc[i][j][1] + bv),
                                  (bf16)(acc[i][j][2] + bv), (bf16)(acc[i][j][3] + bv) };
                    *(bf16x4*)(v + ((size_t)(b * NH + h) * HD + d) * NSEQ + ns) = pv;
                }
            }
        }
    }
}

// ---------------- flash attention, fixed-m softmax, 32x32 MFMA ----------------
// q (pre-scaled by 0.125*log2e): [B,H,N,D]; k: [B,H,N,D]; v: [B,H,D,N]; o: [B,N,C]
// P = exp2(S_log2 - M_FIX); denominator on the MFMA pipe via ones-row A-operand.
// T4 counted-vmcnt 3-buffer KV pipeline: top of iter kt waits vmcnt(4) (stage kt
// landed; stage kt+1 in flight), barriers, then issues stage kt+2 into buf (kt+2)%3
// (= buf read at kt-1; its ds_reads completed before kt-1's MFMAs; overwrite issues
// after the kt-top barrier -> race-free). Queue never drains in the loop.
// Q staged into buf2; qf rows are wave-local (wave w stages rows w*32..w*32+31),
// lgkmcnt(0) before the loop protects buf2's first overwrite at kt=0.
// Grid: 1D 768 blocks, XCD-locality map (12 heads x 256KB = 3MB < 4MB L2/XCD).
__global__ __launch_bounds__(256) void attn_kernel(
    const bf16* __restrict__ q, const bf16* __restrict__ k,
    const bf16* __restrict__ v, bf16* __restrict__ o)
{
    __shared__ alignas(16) bf16 sKV[3][8192];
    const int tid  = threadIdx.x;
    const int lane = tid & 63;
    const int w    = tid >> 6;
    const int h    = lane >> 5;
    const int l32  = lane & 31;

    const int wg  = blockIdx.x;          // 0..767
    const int xcd = wg & 7;
    const int idx = wg >> 3;             // 0..95
    const int bh  = xcd * 12 + (idx % 12);
    const int qt  = idx / 12;            // 0..7
    const int b = bh / NH, hh = bh - b * NH;

    const bf16* qb = q + ((size_t)bh * NSEQ + qt * 128) * HD;
    const bf16* kb = k + (size_t)bh * NSEQ * HD;
    const bf16* vb = v + (size_t)bh * HD * NSEQ;

    // ---- stage Q (4 loads/wave) into buf2, then KV0 -> buf0, KV1 -> buf1
#pragma unroll
    for (int i = 0; i < 4; i++) {
        int slot = w * 256 + i * 64 + lane;
        int r = slot >> 3, cs = slot & 7;
        __builtin_amdgcn_global_load_lds(GLB_CAST(qb + r * HD + ((cs ^ (r & 7)) * 8)),
                                         LDS_CAST(&sKV[2][(w * 256 + i * 64) * 8]), 16, 0, 0);
    }
    auto stageKV = [&](int kt, int buf) {   // 4 loads/wave
#pragma unroll
        for (int i = 0; i < 2; i++) {
            int slot = w * 128 + i * 64 + lane;
            int r = slot >> 3, cs = slot & 7;
            int cc = (cs ^ (r & 7)) * 8;
            __builtin_amdgcn_global_load_lds(GLB_CAST(kb + (size_t)(kt * 64 + r) * HD + cc),
                                             LDS_CAST(&sKV[buf][(w * 128 + i * 64) * 8]), 16, 0, 0);
            __builtin_amdgcn_global_load_lds(GLB_CAST(vb + (size_t)r * NSEQ + kt * 64 + cc),
                                             LDS_CAST(&sKV[buf][4096 + (w * 128 + i * 64) * 8]), 16, 0, 0);
        }
    };
    stageKV(0, 0);
    stageKV(1, 1);
    // outstanding: Q(4,oldest) KV0(4) KV1(4): vmcnt(4) -> Q,KV0 landed, KV1 in flight
    asm volatile("s_waitcnt vmcnt(4)" ::: "memory");
    __builtin_amdgcn_sched_barrier(0);
    __builtin_amdgcn_s_barrier();

    // hoist Q fragments (wave-local rows) then fence before buf2 is restaged
    bf16x8 qf[4];
    {
        int row = w * 32 + l32, rxq = row & 7;
#pragma unroll
        for (int cd = 0; cd < 4; cd++)
            qf[cd] = *(const bf16x8*)(&sKV[2][(row * 8 + ((2 * cd + h) ^ rxq)) * 8]);
    }
    asm volatile("s_waitcnt lgkmcnt(0)" ::: "memory");
    __builtin_amdgcn_sched_barrier(0);

    bf16x8 onesA;
#pragma unroll
    for (int i = 0; i < 8; i++) onesA[i] = (bf16)1.0f;

    f32x16 accO[2], accL;
#pragma unroll
    for (int dt = 0; dt < 2; dt++)
#pragma unroll
        for (int i = 0; i < 16; i++) accO[dt][i] = 0.f;
#pragma unroll
    for (int i = 0; i < 16; i++) accL[i] = 0.f;

    const int rx = l32 & 7;
    int bufc = 0;                         // kt % 3

    for (int kt = 0; kt < 16; kt++) {
        if (kt) {
            if (kt < 15) asm volatile("s_waitcnt vmcnt(4)" ::: "memory");
            else         asm volatile("s_waitcnt vmcnt(0)" ::: "memory");
            __builtin_amdgcn_sched_barrier(0);
            __builtin_amdgcn_s_barrier();
            __builtin_amdgcn_sched_barrier(0);
        }
        if (kt + 2 < 16) {
            int b2 = bufc + 2; if (b2 >= 3) b2 -= 3;
            stageKV(kt + 2, b2);
        }
        const bf16* sKc = &sKV[bufc][0];
        const bf16* sVc = &sKV[bufc][4096];

        // ---- S^T = K . Q^T (kvt-inner: two chains alternate)
        f32x16 accS[2];
#pragma unroll
        for (int kvt = 0; kvt < 2; kvt++)
#pragma unroll
            for (int i = 0; i < 16; i++) accS[kvt][i] = 0.f;
        __builtin_amdgcn_s_setprio(1);
#pragma unroll
        for (int cd = 0; cd < 4; cd++)
#pragma unroll
            for (int kvt = 0; kvt < 2; kvt++) {
                int row = kvt * 32 + l32;
                bf16x8 kf = *(const bf16x8*)(sKc + (row * 8 + ((2 * cd + h) ^ rx)) * 8);
                accS[kvt] = MFMA32(kf, qf[cd], accS[kvt]);
            }
        __builtin_amdgcn_s_setprio(0);

        // ---- P = exp2(S - M_FIX): independent per element, pack straight to bf16
        u32 pr[2][4][2];
#pragma unroll
        for (int kvt = 0; kvt < 2; kvt++)
#pragma unroll
            for (int g = 0; g < 4; g++) {
                pr[kvt][g][0] = pkbf(EXPF(accS[kvt][4 * g + 0] - M_FIX),
                                     EXPF(accS[kvt][4 * g + 1] - M_FIX));
                pr[kvt][g][1] = pkbf(EXPF(accS[kvt][4 * g + 2] - M_FIX),
                                     EXPF(accS[kvt][4 * g + 3] - M_FIX));
            }

        bf16x8 pf[4];
#pragma unroll
        for (int c = 0; c < 4; c++) {
            int kvt = c >> 1, c1 = c & 1;
            u32 u00 = pr[kvt][2 * c1][0],     u01 = pr[kvt][2 * c1][1];
            u32 u10 = pr[kvt][2 * c1 + 1][0], u11 = pr[kvt][2 * c1 + 1][1];
            u32 y0 = h ? u10 : u00, y1 = h ? u11 : u01;
            u32 z0 = h ? u00 : u10, z1 = h ? u01 : u11;
            u32 w0 = (u32)__shfl_xor((int)z0, 32);
            u32 w1 = (u32)__shfl_xor((int)z1, 32);
            u32x4 fv = { h ? w0 : y0, h ? w1 : y1, h ? y0 : w0, h ? y1 : w1 };
            pf[c] = __builtin_bit_cast(bf16x8, fv);
        }

        // ---- O^T += V^T . P^T ; l += 1^T . P^T (3 chains alternate)
        __builtin_amdgcn_s_setprio(1);
#pragma unroll
        for (int c = 0; c < 4; c++) {
#pragma unroll
            for (int dt = 0; dt < 2; dt++) {
                int row = dt * 32 + l32;
                bf16x8 vf = *(const bf16x8*)(sVc + (row * 8 + ((2 * c + h) ^ rx)) * 8);
                accO[dt] = MFMA32(vf, pf[c], accO[dt]);
            }
            accL = MFMA32(onesA, pf[c], accL);
        }
        __builtin_amdgcn_s_setprio(0);

        bufc += 1; if (bufc >= 3) bufc -= 3;
    }

    float inv = 1.f / accL[0];
    bf16* ob = o + ((size_t)b * NSEQ + qt * 128 + w * 32 + l32) * CDIM + hh * HD;
#pragma unroll
    for (int dt = 0; dt < 2; dt++)
#pragma unroll
        for (int g = 0; g < 4; g++) {
            bf16x4 t = { (bf16)(accO[dt][4 * g + 0] * inv), (bf16)(accO[dt][4 * g + 1] * inv),
                         (bf16)(accO[dt][4 * g + 2] * inv), (bf16)(accO[dt][4 * g + 3] * inv) };
            *(bf16x4*)(ob + dt * 32 + 8 * g + 4 * h) = t;
        }
}

// ---------------------------------------------------------------
extern "C" void kernel_launch(void* const* d_in, const int* in_sizes, int n_in,
                              void* d_out, int out_size, void* d_ws, size_t ws_size,
                              hipStream_t stream)
{
    const float* x     = (const float*)d_in[0];
    const float* Wqkv  = (const float*)d_in[1];
    const float* bqkv  = (const float*)d_in[2];
    const float* Wproj = (const float*)d_in[3];
    const float* bproj = (const float*)d_in[4];
    float* out = (float*)d_out;

    char* ws = (char*)d_ws;
    const size_t MC2 = (size_t)MTOT * CDIM * 2;
    bf16* xb     = (bf16*)ws; ws += MC2;
    bf16* wqkvt  = (bf16*)ws; ws += (size_t)NC3 * CDIM * 2;
    bf16* wprojt = (bf16*)ws; ws += (size_t)CDIM * CDIM * 2;
    bf16* qw     = (bf16*)ws; ws += MC2;
    bf16* kw     = (bf16*)ws; ws += MC2;
    bf16* vw     = (bf16*)ws; ws += MC2;
    bf16* ow     = (bf16*)ws; ws += MC2;

    // fused prep: transposes (blocks 0..TT-1) + x cast (blocks TT..TT+CASTB-1)
    prep_kernel<<<dim3(TT + CASTB), dim3(256), 0, stream>>>(x, xb, Wqkv, wqkvt, Wproj, wprojt);

    // QKV: 256x128 tiles -> 18*32 = 576 blocks (%8==0 for XCD swizzle)
    gemm_kernel<1, 256><<<dim3((NC3 / 128) * (MTOT / 256)), dim3(512), 0, stream>>>(
        xb, wqkvt, bqkv, nullptr, qw, kw, vw, NC3, CDIM);

    attn_kernel<<<dim3(768), dim3(256), 0, stream>>>(qw, kw, vw, ow);

    // proj: 128x128 tiles -> 6*64 = 384 blocks (%8==0)
    gemm_kernel<0, 128><<<dim3((CDIM / 128) * (MTOT / 128)), dim3(256), 0, stream>>>(
        ow, wprojt, bproj, out, nullptr, nullptr, nullptr, CDIM, CDIM);
}

// Round 8
// 190.470 us; speedup vs baseline: 1.0758x; 1.0173x over previous
//
#include <hip/hip_runtime.h>
#include <hip/hip_bf16.h>
#include <cstdint>
#include <cstddef>

typedef __bf16 bf16;
typedef __bf16 bf16x8 __attribute__((ext_vector_type(8)));
typedef __bf16 bf16x4 __attribute__((ext_vector_type(4)));
typedef __bf16 bf16x2 __attribute__((ext_vector_type(2)));
typedef float f32x4 __attribute__((ext_vector_type(4)));
typedef float f32x16 __attribute__((ext_vector_type(16)));
typedef unsigned int u32;
typedef u32 u32x4 __attribute__((ext_vector_type(4)));

#define LDS_CAST(p) (__attribute__((address_space(3))) void*)(p)
#define GLB_CAST(p) (const __attribute__((address_space(1))) void*)(p)
#define MFMA16(a, b, c) __builtin_amdgcn_mfma_f32_16x16x32_bf16(a, b, c, 0, 0, 0)
#define MFMA32(a, b, c) __builtin_amdgcn_mfma_f32_32x32x16_bf16(a, b, c, 0, 0, 0)

#if __has_builtin(__builtin_amdgcn_exp2f)
#define EXPF(x) __builtin_amdgcn_exp2f(x)
#define QK_SCALE 0.18033688011112042f  /* 0.125 * log2(e) */
#else
#define EXPF(x) __expf(x)
#define QK_SCALE 0.125f
#endif

static constexpr int BATCH = 8;
static constexpr int NSEQ  = 1024;
static constexpr int CDIM  = 768;
static constexpr int NH    = 12;
static constexpr int HD    = 64;
static constexpr int MTOT  = BATCH * NSEQ;   // 8192
static constexpr int NC3   = 3 * CDIM;       // 2304

// Fixed softmax shift (log2 domain; scale*log2e folded into Q).
static constexpr float M_FIX = 12.0f;

// prep kernel work partition
static constexpr int TQKV  = (NC3 / 32) * (CDIM / 32);   // 1728 transpose tiles
static constexpr int TPROJ = (CDIM / 32) * (CDIM / 32);  // 576
static constexpr int TT    = TQKV + TPROJ;               // 2304
static constexpr int N4    = MTOT * CDIM / 4;            // 1572864 float4 items
static constexpr int CASTB = (N4 + 255) / 256;           // 6144 cast blocks

__device__ inline u32 pkbf(float a, float b) {
    bf16x2 t = { (bf16)a, (bf16)b };
    return __builtin_bit_cast(u32, t);
}

// ---------- fused prep: x cast + Wqkv^T cast + Wproj^T cast (1 launch) ----------
__global__ void prep_kernel(const float* __restrict__ x, bf16* __restrict__ xb,
                            const float* __restrict__ Wqkv, bf16* __restrict__ wqkvt,
                            const float* __restrict__ Wproj, bf16* __restrict__ wprojt)
{
    __shared__ float tile[32][33];
    const int bid = blockIdx.x;
    if (bid < TT) {
        // tiled transpose-cast: dst[n][k] = (bf16)src[k][n]; coalesced both sides
        const float* src; bf16* dst; int N, n0, k0;
        if (bid < TQKV) { src = Wqkv;  dst = wqkvt;  N = NC3;
                          n0 = (bid % (NC3 / 32)) * 32;  k0 = (bid / (NC3 / 32)) * 32; }
        else { int t = bid - TQKV; src = Wproj; dst = wprojt; N = CDIM;
               n0 = (t % (CDIM / 32)) * 32;  k0 = (t / (CDIM / 32)) * 32; }
        const int K = CDIM;
        const int tx = threadIdx.x & 31, ty = threadIdx.x >> 5;   // ty 0..7
#pragma unroll
        for (int p = 0; p < 4; p++)
            tile[ty + p * 8][tx] = src[(size_t)(k0 + ty + p * 8) * N + n0 + tx];
        __syncthreads();
#pragma unroll
        for (int p = 0; p < 4; p++)
            dst[(size_t)(n0 + ty + p * 8) * K + k0 + tx] = (bf16)tile[tx][ty + p * 8];
    } else {
        int i = (bid - TT) * 256 + threadIdx.x;
        if (i < N4) {
            float4 v = ((const float4*)x)[i];
            bf16x4 o = { (bf16)v.x, (bf16)v.y, (bf16)v.z, (bf16)v.w };
            ((bf16x4*)xb)[i] = o;
        }
    }
}

// ---------------- GEMM: C[M,Nd] = A[M,K] @ Bt[Nd,K]^T + bias ----------------
// 128x128 tile, 256 thr (4 waves, 2Mx2N), per-wave 64x64, BK=32.
// T4 depth-2 counted-vmcnt, 3 LDS buffers of 16KB (48KB -> 3 blocks/CU TLP):
//   iter t: issue STAGE(t+2) into buf (t+2)%3; ds_read buf t%3; MFMA;
//   then s_waitcnt vmcnt(4) (tile t+1 landed, stage t+2's 4 loads stay in
//   flight) + barrier. Queue never drains in the main loop; each stage gets
//   2 compute phases + 2 barriers of slack. Race proof: buf (t+2)%3 was last
//   read at iter t-1 (ds_reads complete before its MFMAs; its end barrier
//   precedes this STAGE issue).
// LDS swizzle: slot (row, cs) holds global chunk cs ^ ((row>>1)&3); reads at
// chunk quad ^ ((l16>>1)&3) -> 2-way (free). Verified: SQ_LDS_BANK_CONFLICT = 0.
// MODE 0: fp32 out (proj). MODE 1: bf16 q/k -> [B,H,N,D] (q pre-scaled), v -> [B,H,D,N]
template <int MODE>
__global__ __launch_bounds__(256, 4) void gemm_kernel(
    const bf16* __restrict__ A, const bf16* __restrict__ Bt,
    const float* __restrict__ bias, float* __restrict__ outf,
    bf16* __restrict__ q, bf16* __restrict__ kk, bf16* __restrict__ v,
    int Ndim, int K)
{
    constexpr int BM = 128, BN = 128;
    __shared__ alignas(16) bf16 sAB[3][(BM + BN) * 32];   // 3 x 16KB
    const int tid  = threadIdx.x;
    const int lane = tid & 63;
    const int quad = lane >> 4;
    const int l16  = lane & 15;
    const int wid  = tid >> 6;
    const int wmI  = wid >> 1;
    const int wnI  = wid & 1;

    const int wg = blockIdx.x;
    const int x  = (wg & 7) * (gridDim.x >> 3) + (wg >> 3);
    const int nTn = Ndim >> 7;
    const int tn = x % nTn, tm = x / nTn;
    const int tmB = tm * BM, tnB = tn * BN;

    int aoff[4], boff[4];
    {
        const int xr = ((quad ^ ((l16 >> 1) & 3)) << 3);
#pragma unroll
        for (int i = 0; i < 4; i++) aoff[i] = (wmI * 64 + i * 16 + l16) * 32 + xr;
#pragma unroll
        for (int j = 0; j < 4; j++) boff[j] = BM * 32 + (wnI * 64 + j * 16 + l16) * 32 + xr;
    }

    const int r0 = tid >> 2;                          // 0..63
    const int c0 = (tid & 3) ^ ((r0 >> 1) & 3);
    const bf16* gA0 = A  + (size_t)(tmB + r0) * K + c0 * 8;
    const bf16* gA1 = gA0 + (size_t)64 * K;
    const bf16* gB0 = Bt + (size_t)(tnB + r0) * K + c0 * 8;
    const bf16* gB1 = gB0 + (size_t)64 * K;
    const int ldsb = (tid & ~63) * 8;                 // wave-uniform slot base (elems)

    auto STAGE = [&](int t, int bsel) {               // 4 loads/thread
        const int k0 = t << 5;
        bf16* d = &sAB[bsel][0] + ldsb;
        __builtin_amdgcn_global_load_lds(GLB_CAST(gA0 + k0), LDS_CAST(d),        16, 0, 0);
        __builtin_amdgcn_global_load_lds(GLB_CAST(gA1 + k0), LDS_CAST(d + 2048), 16, 0, 0);
        __builtin_amdgcn_global_load_lds(GLB_CAST(gB0 + k0), LDS_CAST(d + 4096), 16, 0, 0);
        __builtin_amdgcn_global_load_lds(GLB_CAST(gB1 + k0), LDS_CAST(d + 6144), 16, 0, 0);
    };

    const f32x4 fzero = {0.f, 0.f, 0.f, 0.f};
    f32x4 acc[4][4];
#pragma unroll
    for (int i = 0; i < 4; i++)
#pragma unroll
        for (int j = 0; j < 4; j++) acc[i][j] = fzero;

    const int NT = K >> 5;   // 24 for K=768
    STAGE(0, 0);
    STAGE(1, 1);
    // outstanding: stage0(4, oldest) + stage1(4): vmcnt(4) -> tile 0 landed
    asm volatile("s_waitcnt vmcnt(4)" ::: "memory");
    __builtin_amdgcn_sched_barrier(0);
    __builtin_amdgcn_s_barrier();

    int bufc = 0;                                     // t % 3
    for (int t = 0; t < NT; ++t) {
        if (t + 2 < NT) {
            int b2 = bufc + 2; if (b2 >= 3) b2 -= 3;
            STAGE(t + 2, b2);
        }

        const bf16* buf = &sAB[bufc][0];
        bf16x8 af[4], bfr[4];
#pragma unroll
        for (int i = 0; i < 4; i++) af[i]  = *(const bf16x8*)(buf + aoff[i]);
#pragma unroll
        for (int j = 0; j < 4; j++) bfr[j] = *(const bf16x8*)(buf + boff[j]);

        __builtin_amdgcn_s_setprio(1);
#pragma unroll
        for (int i = 0; i < 4; i++)
#pragma unroll
            for (int j = 0; j < 4; j++) acc[i][j] = MFMA16(af[i], bfr[j], acc[i][j]);
        __builtin_amdgcn_s_setprio(0);

        if (t < NT - 1) {
            // tile t+1 must have landed; stage(t+2)'s 4 loads stay in flight
            if (t + 2 < NT) asm volatile("s_waitcnt vmcnt(4)" ::: "memory");
            else            asm volatile("s_waitcnt vmcnt(0)" ::: "memory");
            __builtin_amdgcn_sched_barrier(0);
            __builtin_amdgcn_s_barrier();
            __builtin_amdgcn_sched_barrier(0);
        }
        bufc += 1; if (bufc >= 3) bufc -= 3;
    }

    if (MODE == 0) {
#pragma unroll
        for (int i = 0; i < 4; i++) {
            int row = tmB + wmI * 64 + i * 16 + quad * 4;
#pragma unroll
            for (int j = 0; j < 4; j++) {
                int col = tnB + wnI * 64 + j * 16 + l16;
                float bv = bias[col];
                float* op = outf + (size_t)row * Ndim + col;
#pragma unroll
                for (int r = 0; r < 4; r++) op[(size_t)r * Ndim] = acc[i][j][r] + bv;
            }
        }
    } else {
#pragma unroll
        for (int i = 0; i < 4; i++) {
            int row = tmB + wmI * 64 + i * 16 + quad * 4;
            int b  = row >> 10;
            int ns = row & 1023;
#pragma unroll
            for (int j = 0; j < 4; j++) {
                int col = tnB + wnI * 64 + j * 16 + l16;
                int t3  = col / 768;
                int rem = col - t3 * 768;
                int h = rem >> 6;
                int d = rem & 63;
                float bv = bias[col];
                if (t3 == 0) {
                    bf16* qp = q + ((size_t)(b * NH + h) * NSEQ + ns) * HD + d;
#pragma unroll
                    for (int r = 0; r < 4; r++)
                        qp[(size_t)r * HD] = (bf16)((acc[i][j][r] + bv) * (float)QK_SCALE);
                } else if (t3 == 1) {
                    bf16* kp = kk + ((size_t)(b * NH + h) * NSEQ + ns) * HD + d;
#pragma unroll
                    for (int r = 0; r < 4; r++) kp[(size_t)r * HD] = (bf16)(acc[i][j][r] + bv);
                } else {
                    bf16x4 pv = { (bf16)(acc[i][j][0] + bv), (bf16)(acc[i][j][1] + bv),
                                  (bf16)(acc[i][j][2] + bv), (bf16)(acc[i][j][3] + bv) };
                    *(bf16x4*)(v + ((size_t)(b * NH + h) * HD + d) * NSEQ + ns) = pv;
                }
            }
        }
    }
}

// ---------------- flash attention, fixed-m softmax, 32x32 MFMA ----------------
// q (pre-scaled by 0.125*log2e): [B,H,N,D]; k: [B,H,N,D]; v: [B,H,D,N]; o: [B,N,C]
// P = exp2(S_log2 - M_FIX); denominator on the MFMA pipe via ones-row A-operand.
// T4 counted-vmcnt 3-buffer KV pipeline (verified round 7). Grid: 1D 768 blocks,
// XCD-locality map (12 heads x 256KB = 3MB < 4MB L2/XCD).
__global__ __launch_bounds__(256) void attn_kernel(
    const bf16* __restrict__ q, const bf16* __restrict__ k,
    const bf16* __restrict__ v, bf16* __restrict__ o)
{
    __shared__ alignas(16) bf16 sKV[3][8192];
    const int tid  = threadIdx.x;
    const int lane = tid & 63;
    const int w    = tid >> 6;
    const int h    = lane >> 5;
    const int l32  = lane & 31;

    const int wg  = blockIdx.x;          // 0..767
    const int xcd = wg & 7;
    const int idx = wg >> 3;             // 0..95
    const int bh  = xcd * 12 + (idx % 12);
    const int qt  = idx / 12;            // 0..7
    const int b = bh / NH, hh = bh - b * NH;

    const bf16* qb = q + ((size_t)bh * NSEQ + qt * 128) * HD;
    const bf16* kb = k + (size_t)bh * NSEQ * HD;
    const bf16* vb = v + (size_t)bh * HD * NSEQ;

    // ---- stage Q (4 loads/wave) into buf2, then KV0 -> buf0, KV1 -> buf1
#pragma unroll
    for (int i = 0; i < 4; i++) {
        int slot = w * 256 + i * 64 + lane;
        int r = slot >> 3, cs = slot & 7;
        __builtin_amdgcn_global_load_lds(GLB_CAST(qb + r * HD + ((cs ^ (r & 7)) * 8)),
                                         LDS_CAST(&sKV[2][(w * 256 + i * 64) * 8]), 16, 0, 0);
    }
    auto stageKV = [&](int kt, int buf) {   // 4 loads/wave
#pragma unroll
        for (int i = 0; i < 2; i++) {
            int slot = w * 128 + i * 64 + lane;
            int r = slot >> 3, cs = slot & 7;
            int cc = (cs ^ (r & 7)) * 8;
            __builtin_amdgcn_global_load_lds(GLB_CAST(kb + (size_t)(kt * 64 + r) * HD + cc),
                                             LDS_CAST(&sKV[buf][(w * 128 + i * 64) * 8]), 16, 0, 0);
            __builtin_amdgcn_global_load_lds(GLB_CAST(vb + (size_t)r * NSEQ + kt * 64 + cc),
                                             LDS_CAST(&sKV[buf][4096 + (w * 128 + i * 64) * 8]), 16, 0, 0);
        }
    };
    stageKV(0, 0);
    stageKV(1, 1);
    // outstanding: Q(4,oldest) KV0(4) KV1(4): vmcnt(4) -> Q,KV0 landed, KV1 in flight
    asm volatile("s_waitcnt vmcnt(4)" ::: "memory");
    __builtin_amdgcn_sched_barrier(0);
    __builtin_amdgcn_s_barrier();

    // hoist Q fragments (wave-local rows) then fence before buf2 is restaged
    bf16x8 qf[4];
    {
        int row = w * 32 + l32, rxq = row & 7;
#pragma unroll
        for (int cd = 0; cd < 4; cd++)
            qf[cd] = *(const bf16x8*)(&sKV[2][(row * 8 + ((2 * cd + h) ^ rxq)) * 8]);
    }
    asm volatile("s_waitcnt lgkmcnt(0)" ::: "memory");
    __builtin_amdgcn_sched_barrier(0);

    bf16x8 onesA;
#pragma unroll
    for (int i = 0; i < 8; i++) onesA[i] = (bf16)1.0f;

    f32x16 accO[2], accL;
#pragma unroll
    for (int dt = 0; dt < 2; dt++)
#pragma unroll
        for (int i = 0; i < 16; i++) accO[dt][i] = 0.f;
#pragma unroll
    for (int i = 0; i < 16; i++) accL[i] = 0.f;

    const int rx = l32 & 7;
    int bufc = 0;                         // kt % 3

    for (int kt = 0; kt < 16; kt++) {
        if (kt) {
            if (kt < 15) asm volatile("s_waitcnt vmcnt(4)" ::: "memory");
            else         asm volatile("s_waitcnt vmcnt(0)" ::: "memory");
            __builtin_amdgcn_sched_barrier(0);
            __builtin_amdgcn_s_barrier();
            __builtin_amdgcn_sched_barrier(0);
        }
        if (kt + 2 < 16) {
            int b2 = bufc + 2; if (b2 >= 3) b2 -= 3;
            stageKV(kt + 2, b2);
        }
        const bf16* sKc = &sKV[bufc][0];
        const bf16* sVc = &sKV[bufc][4096];

        // ---- S^T = K . Q^T (kvt-inner: two chains alternate)
        f32x16 accS[2];
#pragma unroll
        for (int kvt = 0; kvt < 2; kvt++)
#pragma unroll
            for (int i = 0; i < 16; i++) accS[kvt][i] = 0.f;
        __builtin_amdgcn_s_setprio(1);
#pragma unroll
        for (int cd = 0; cd < 4; cd++)
#pragma unroll
            for (int kvt = 0; kvt < 2; kvt++) {
                int row = kvt * 32 + l32;
                bf16x8 kf = *(const bf16x8*)(sKc + (row * 8 + ((2 * cd + h) ^ rx)) * 8);
                accS[kvt] = MFMA32(kf, qf[cd], accS[kvt]);
            }
        __builtin_amdgcn_s_setprio(0);

        // ---- P = exp2(S - M_FIX): independent per element, pack straight to bf16
        u32 pr[2][4][2];
#pragma unroll
        for (int kvt = 0; kvt < 2; kvt++)
#pragma unroll
            for (int g = 0; g < 4; g++) {
                pr[kvt][g][0] = pkbf(EXPF(accS[kvt][4 * g + 0] - M_FIX),
                                     EXPF(accS[kvt][4 * g + 1] - M_FIX));
                pr[kvt][g][1] = pkbf(EXPF(accS[kvt][4 * g + 2] - M_FIX),
                                     EXPF(accS[kvt][4 * g + 3] - M_FIX));
            }

        bf16x8 pf[4];
#pragma unroll
        for (int c = 0; c < 4; c++) {
            int kvt = c >> 1, c1 = c & 1;
            u32 u00 = pr[kvt][2 * c1][0],     u01 = pr[kvt][2 * c1][1];
            u32 u10 = pr[kvt][2 * c1 + 1][0], u11 = pr[kvt][2 * c1 + 1][1];
            u32 y0 = h ? u10 : u00, y1 = h ? u11 : u01;
            u32 z0 = h ? u00 : u10, z1 = h ? u01 : u11;
            u32 w0 = (u32)__shfl_xor((int)z0, 32);
            u32 w1 = (u32)__shfl_xor((int)z1, 32);
            u32x4 fv = { h ? w0 : y0, h ? w1 : y1, h ? y0 : w0, h ? y1 : w1 };
            pf[c] = __builtin_bit_cast(bf16x8, fv);
        }

        // ---- O^T += V^T . P^T ; l += 1^T . P^T (3 chains alternate)
        __builtin_amdgcn_s_setprio(1);
#pragma unroll
        for (int c = 0; c < 4; c++) {
#pragma unroll
            for (int dt = 0; dt < 2; dt++) {
                int row = dt * 32 + l32;
                bf16x8 vf = *(const bf16x8*)(sVc + (row * 8 + ((2 * c + h) ^ rx)) * 8);
                accO[dt] = MFMA32(vf, pf[c], accO[dt]);
            }
            accL = MFMA32(onesA, pf[c], accL);
        }
        __builtin_amdgcn_s_setprio(0);

        bufc += 1; if (bufc >= 3) bufc -= 3;
    }

    float inv = 1.f / accL[0];
    bf16* ob = o + ((size_t)b * NSEQ + qt * 128 + w * 32 + l32) * CDIM + hh * HD;
#pragma unroll
    for (int dt = 0; dt < 2; dt++)
#pragma unroll
        for (int g = 0; g < 4; g++) {
            bf16x4 t = { (bf16)(accO[dt][4 * g + 0] * inv), (bf16)(accO[dt][4 * g + 1] * inv),
                         (bf16)(accO[dt][4 * g + 2] * inv), (bf16)(accO[dt][4 * g + 3] * inv) };
            *(bf16x4*)(ob + dt * 32 + 8 * g + 4 * h) = t;
        }
}

// ---------------------------------------------------------------
extern "C" void kernel_launch(void* const* d_in, const int* in_sizes, int n_in,
                              void* d_out, int out_size, void* d_ws, size_t ws_size,
                              hipStream_t stream)
{
    const float* x     = (const float*)d_in[0];
    const float* Wqkv  = (const float*)d_in[1];
    const float* bqkv  = (const float*)d_in[2];
    const float* Wproj = (const float*)d_in[3];
    const float* bproj = (const float*)d_in[4];
    float* out = (float*)d_out;

    char* ws = (char*)d_ws;
    const size_t MC2 = (size_t)MTOT * CDIM * 2;
    bf16* xb     = (bf16*)ws; ws += MC2;
    bf16* wqkvt  = (bf16*)ws; ws += (size_t)NC3 * CDIM * 2;
    bf16* wprojt = (bf16*)ws; ws += (size_t)CDIM * CDIM * 2;
    bf16* qw     = (bf16*)ws; ws += MC2;
    bf16* kw     = (bf16*)ws; ws += MC2;
    bf16* vw     = (bf16*)ws; ws += MC2;
    bf16* ow     = (bf16*)ws; ws += MC2;

    // fused prep: transposes (blocks 0..TT-1) + x cast (blocks TT..TT+CASTB-1)
    prep_kernel<<<dim3(TT + CASTB), dim3(256), 0, stream>>>(x, xb, Wqkv, wqkvt, Wproj, wprojt);

    // QKV: 128x128 tiles -> 18*64 = 1152 blocks (%8==0 for XCD swizzle), 4.5/CU
    gemm_kernel<1><<<dim3((NC3 / 128) * (MTOT / 128)), dim3(256), 0, stream>>>(
        xb, wqkvt, bqkv, nullptr, qw, kw, vw, NC3, CDIM);

    attn_kernel<<<dim3(768), dim3(256), 0, stream>>>(qw, kw, vw, ow);

    // proj: 128x128 tiles -> 6*64 = 384 blocks (%8==0)
    gemm_kernel<0><<<dim3((CDIM / 128) * (MTOT / 128)), dim3(256), 0, stream>>>(
        ow, wprojt, bproj, out, nullptr, nullptr, nullptr, CDIM, CDIM);
}